// Round 4
// baseline (68.878 us; speedup 1.0000x reference)
//
#include <hip/hip_runtime.h>

#define K 16

// One wave per output row. Everything in registers, zero LDS, zero barriers.
//
// Math: p_j = sum_{t<=j} T^t v ; out row i needs x = p_{n-1-i} = s(m), m = n-i,
// where s(m) = S(m) v, S(m) = sum_{t<m} T^t, using S(a+b) = S(a) + T^a S(b):
//   bit-walk m LSB->MSB:  cur <- s(2^k) + T^(2^k) * cur   (if bit k set)
//   chain:  s(2^{k+1}) = s(2^k) + T^(2^k) s(2^k),  T^(2^{k+1}) = (T^(2^k))^2
//
// Register layout (lane = 4*r + g, r=row 0..15, g=col-group 0..3):
//   P  : float4 = T^(2^k)[r][4g..4g+3]   (distributed matrix)
//   sc : float4 = s(2^k)[4g..4g+3]       (column-chunk, replicated across r)
//   cc : float4 = cur[4g..4g+3]
__global__ __launch_bounds__(64) void pe_onewave(
    const float* __restrict__ pos_initial,     // [16,1]
    const float* __restrict__ pos_transition,  // [16,16]
    const float* __restrict__ Wm,              // [E,16]
    const float* __restrict__ bias,            // [E]
    float* __restrict__ out, int n, int E)
{
    const int lane = threadIdx.x;
    const int r = lane >> 2;
    const int g = lane & 3;

    float4 P  = ((const float4*)pos_transition)[lane];     // T[r][4g..4g+3]
    float4 sc = ((const float4*)pos_initial)[g];           // v[4g..4g+3]
    float4 cc = make_float4(0.f, 0.f, 0.f, 0.f);           // s(0) = 0

    const int i = blockIdx.x;
    const int m = n - i;                                   // 1..n

    for (int k = 0; k < 31; ++k) {
        if ((m >> k) & 1) {
            // cur = s(2^k) + P * cur   (matvec via shfl reduce+gather)
            float part = P.x * cc.x + P.y * cc.y + P.z * cc.z + P.w * cc.w;
            part += __shfl_xor(part, 1);
            part += __shfl_xor(part, 2);       // lanes 4r..4r+3 hold y[r]
            cc.x = sc.x + __shfl(part, 16 * g);
            cc.y = sc.y + __shfl(part, 16 * g + 4);
            cc.z = sc.z + __shfl(part, 16 * g + 8);
            cc.w = sc.w + __shfl(part, 16 * g + 12);
        }
        if ((m >> (k + 1)) == 0) break;        // uniform: no higher bits

        // s(2^{k+1}) = s + P s
        {
            float part = P.x * sc.x + P.y * sc.y + P.z * sc.z + P.w * sc.w;
            part += __shfl_xor(part, 1);
            part += __shfl_xor(part, 2);
            sc.x += __shfl(part, 16 * g);
            sc.y += __shfl(part, 16 * g + 4);
            sc.z += __shfl(part, 16 * g + 8);
            sc.w += __shfl(part, 16 * g + 12);
        }
        // P <- P*P : C[r][4g..] = sum_kk A[r][kk] * A[kk][4g..4g+3]
        {
            float4 acc = make_float4(0.f, 0.f, 0.f, 0.f);
            #pragma unroll 16
            for (int kk = 0; kk < 16; ++kk) {
                float a;
                switch (kk & 3) {              // compile-time after unroll
                    case 0:  a = __shfl(P.x, 4 * r + (kk >> 2)); break;
                    case 1:  a = __shfl(P.y, 4 * r + (kk >> 2)); break;
                    case 2:  a = __shfl(P.z, 4 * r + (kk >> 2)); break;
                    default: a = __shfl(P.w, 4 * r + (kk >> 2)); break;
                }
                float bx = __shfl(P.x, 4 * kk + g);
                float by = __shfl(P.y, 4 * kk + g);
                float bz = __shfl(P.z, 4 * kk + g);
                float bw = __shfl(P.w, 4 * kk + g);
                acc.x += a * bx; acc.y += a * by; acc.z += a * bz; acc.w += a * bw;
            }
            P = acc;
        }
    }

    // Replicate x = cur into all lanes: x4[q] = cur[4q..4q+3] (held at lane g=q)
    float4 x0, x1, x2, x3;
    x0.x = __shfl(cc.x, 0); x0.y = __shfl(cc.y, 0); x0.z = __shfl(cc.z, 0); x0.w = __shfl(cc.w, 0);
    x1.x = __shfl(cc.x, 1); x1.y = __shfl(cc.y, 1); x1.z = __shfl(cc.z, 1); x1.w = __shfl(cc.w, 1);
    x2.x = __shfl(cc.x, 2); x2.y = __shfl(cc.y, 2); x2.z = __shfl(cc.z, 2); x2.w = __shfl(cc.w, 2);
    x3.x = __shfl(cc.x, 3); x3.y = __shfl(cc.y, 3); x3.z = __shfl(cc.z, 3); x3.w = __shfl(cc.w, 3);

    // Epilogue: out[i][e] = bias[e] + W[e] . x
    for (int e = lane; e < E; e += 64) {
        const float4* w4 = (const float4*)(Wm + e * K);
        float4 w0 = w4[0], w1 = w4[1], w2 = w4[2], w3 = w4[3];
        float acc = bias[e];
        acc += w0.x * x0.x + w0.y * x0.y + w0.z * x0.z + w0.w * x0.w;
        acc += w1.x * x1.x + w1.y * x1.y + w1.z * x1.z + w1.w * x1.w;
        acc += w2.x * x2.x + w2.y * x2.y + w2.z * x2.z + w2.w * x2.w;
        acc += w3.x * x3.x + w3.y * x3.y + w3.z * x3.z + w3.w * x3.w;
        out[i * E + e] = acc;
    }
}

extern "C" void kernel_launch(void* const* d_in, const int* in_sizes, int n_in,
                              void* d_out, int out_size, void* d_ws, size_t ws_size,
                              hipStream_t stream) {
    const float* pos_initial    = (const float*)d_in[0];  // [16,1]
    const float* pos_transition = (const float*)d_in[1];  // [16,16]
    const float* W              = (const float*)d_in[2];  // [512,16]
    const float* bias           = (const float*)d_in[3];  // [512]
    const int E = in_sizes[3];          // embed_dim = 512
    const int n = out_size / E;         // seq_len  = 512

    pe_onewave<<<n, 64, 0, stream>>>(pos_initial, pos_transition, W, bias,
                                     (float*)d_out, n, E);
}